// Round 4
// baseline (4721.928 us; speedup 1.0000x reference)
//
#include <hip/hip_runtime.h>

#define NTOK   16384
#define INF    2048
#define OUTF   2048
#define RANK   45
#define GTOK   8
#define NRULES 64
#define KCH    64

// ---------------- Kernel 0: sort tokens by rule (single block) ----------------
__global__ __launch_bounds__(1024) void sort_kernel(
    const int* __restrict__ rid, int* __restrict__ perm)
{
    __shared__ int cnt[NRULES];
    __shared__ int cur[NRULES];
    const int tid = threadIdx.x;
    if (tid < NRULES) cnt[tid] = 0;
    __syncthreads();
    for (int i = tid; i < NTOK; i += 1024) atomicAdd(&cnt[rid[i]], 1);
    __syncthreads();
    if (tid == 0) {
        int s = 0;
        for (int r = 0; r < NRULES; ++r) { cur[r] = s; s += cnt[r]; }
    }
    __syncthreads();
    for (int i = tid; i < NTOK; i += 1024) {
        const int r = rid[i];
        const int p = atomicAdd(&cur[r], 1);
        perm[p] = i;
    }
}

// ---------------- Kernel A: t = x @ shared_in ----------------
// 256 blocks x 256 thr; tile 64 rows x 48 cols; micro-tile 4r x 3c.
// 12 FMA per (1 ds_b128 + 3 ds_b32); reg-prefetch next K-chunk.
__global__ __launch_bounds__(256) void t_gemm3(
    const float* __restrict__ x, const float* __restrict__ si, float* __restrict__ t)
{
    __shared__ float x_t[KCH][66];     // [k][row], stride 66 -> <=2-way
    __shared__ float si_l[KCH][48];    // [k][col]
    const int tid = threadIdx.x;
    const int rt = tid >> 4, ct = tid & 15;      // 16x16 thread grid
    const int row0 = rt * 4, c0 = ct * 3;        // 64 rows, 48 cols
    const float4* __restrict__ xg = (const float4*)(x + (size_t)blockIdx.x * 64 * INF);

    if (tid < KCH * 3) si_l[tid / 3][RANK + tid % 3] = 0.f;   // zero pad cols 45..47

    float a[4][3];
#pragma unroll
    for (int r = 0; r < 4; ++r)
#pragma unroll
        for (int c = 0; c < 3; ++c) a[r][c] = 0.f;

    float4 px[4];
    float  ps[12];
    // prologue: chunk 0
#pragma unroll
    for (int s = 0; s < 4; ++s) {
        const int i4 = tid + s * 256;                 // row = i4>>4, kq = (i4&15)*4
        px[s] = xg[(i4 >> 4) * (INF / 4) + (i4 & 15)];
    }
#pragma unroll
    for (int s = 0; s < 12; ++s) {
        const int i = tid + s * 256;
        ps[s] = (i < KCH * RANK) ? si[i] : 0.f;
    }

    for (int ch = 0; ch < INF / KCH; ++ch) {
        // regs -> LDS
#pragma unroll
        for (int s = 0; s < 4; ++s) {
            const int i4 = tid + s * 256;
            const int r = i4 >> 4, kq = (i4 & 15) * 4;
            x_t[kq][r] = px[s].x; x_t[kq + 1][r] = px[s].y;
            x_t[kq + 2][r] = px[s].z; x_t[kq + 3][r] = px[s].w;
        }
#pragma unroll
        for (int s = 0; s < 12; ++s) {
            const int i = tid + s * 256;
            if (i < KCH * RANK) si_l[i / RANK][i % RANK] = ps[s];
        }
        __syncthreads();
        // prefetch chunk ch+1
        if (ch + 1 < INF / KCH) {
            const int k0 = (ch + 1) * KCH;
#pragma unroll
            for (int s = 0; s < 4; ++s) {
                const int i4 = tid + s * 256;
                px[s] = xg[(i4 >> 4) * (INF / 4) + (k0 >> 2) + (i4 & 15)];
            }
#pragma unroll
            for (int s = 0; s < 12; ++s) {
                const int i = tid + s * 256;
                ps[s] = (i < KCH * RANK) ? si[(size_t)k0 * RANK + i] : 0.f;
            }
        }
        // compute
#pragma unroll 8
        for (int k = 0; k < KCH; ++k) {
            const float4 xv = *(const float4*)&x_t[k][row0];
            const float s0 = si_l[k][c0], s1 = si_l[k][c0 + 1], s2 = si_l[k][c0 + 2];
            a[0][0] += xv.x * s0; a[0][1] += xv.x * s1; a[0][2] += xv.x * s2;
            a[1][0] += xv.y * s0; a[1][1] += xv.y * s1; a[1][2] += xv.y * s2;
            a[2][0] += xv.z * s0; a[2][1] += xv.z * s1; a[2][2] += xv.z * s2;
            a[3][0] += xv.w * s0; a[3][1] += xv.w * s1; a[3][2] += xv.w * s2;
        }
        __syncthreads();
    }

    if (c0 < RANK) {
#pragma unroll
        for (int r = 0; r < 4; ++r) {
            float* __restrict__ t0 = t + ((size_t)blockIdx.x * 64 + row0 + r) * RANK + c0;
            t0[0] = a[r][0]; t0[1] = a[r][1]; t0[2] = a[r][2];
        }
    }
}

// ---------------- Kernel B: out[perm] = t[perm]@so + gain * vec(V x U^T) ----------------
// block = 8 consecutive SORTED tokens (usually one rule): U/V staged on rule change only.
__global__ __launch_bounds__(256) void fused3(
    const float* __restrict__ x, const int* __restrict__ rid_p,
    const float* __restrict__ so, const float* __restrict__ rU,
    const float* __restrict__ rV, const float* __restrict__ gains,
    const float* __restrict__ t, const int* __restrict__ perm, float* __restrict__ out)
{
    __shared__ __align__(16) float x_lds[INF];
    __shared__ __align__(16) float xu_t[32][68];
    __shared__ __align__(16) float U_t[32][33];
    __shared__ __align__(16) float V_lds[64][68];
    __shared__ float t_lds[GTOK][RANK + 1];
    __shared__ int   sperm[GTOK], srid[GTOK];
    __shared__ float sgain[GTOK];

    const int tid  = threadIdx.x;
    const int p0   = blockIdx.x * GTOK;
    const int c0   = tid & 15;
    const int dgrp = tid >> 4;
    const int cx   = tid & 31;
    const int bg   = tid >> 5;

    if (tid < GTOK) {
        const int i = perm[p0 + tid];
        sperm[tid] = i;
        const int r = rid_p[i];
        srid[tid]  = r;
        sgain[tid] = gains[r];
    }
    __syncthreads();

    // prefetch token 0's x row (single buffer, 8 VGPR)
    float4 px0, px1;
    {
        const float4* __restrict__ xg = (const float4*)(x + (size_t)sperm[0] * INF);
        px0 = xg[tid]; px1 = xg[tid + 256];
    }
    // gather t rows
    for (int i2 = tid; i2 < GTOK * RANK; i2 += 256) {
        const int g = i2 / RANK, r = i2 - g * RANK;
        t_lds[g][r] = t[(size_t)sperm[g] * RANK + r];
    }

    float acc[GTOK][8];
#pragma unroll
    for (int g = 0; g < GTOK; ++g)
#pragma unroll
        for (int j = 0; j < 8; ++j) acc[g][j] = 0.f;

    __syncthreads();

    // ---- base: acc[g][j] += sum_k t[g][k] * so[k][col_j]
#pragma unroll 3
    for (int k = 0; k < RANK; ++k) {
        float sv[8];
#pragma unroll
        for (int jd = 0; jd < 4; ++jd)
#pragma unroll
            for (int jc = 0; jc < 2; ++jc)
                sv[jd * 2 + jc] = so[(size_t)k * OUTF + (dgrp + 16 * jd) * 32 + c0 + 16 * jc];
#pragma unroll
        for (int g = 0; g < GTOK; ++g) {
            const float tv = t_lds[g][k];
#pragma unroll
            for (int j = 0; j < 8; ++j) acc[g][j] += tv * sv[j];
        }
    }

    // ---- adapter
#pragma unroll
    for (int g = 0; g < GTOK; ++g) {
        __syncthreads();   // previous token's LDS readers done
        ((float4*)x_lds)[tid]       = px0;
        ((float4*)x_lds)[tid + 256] = px1;
        const bool newrule = (g == 0) || (srid[g] != srid[g - 1]);   // block-uniform
        if (newrule) {
            const float4* __restrict__ Ug = (const float4*)(rU + (size_t)srid[g] * 1024);
            const float4* __restrict__ Vg = (const float4*)(rV + (size_t)srid[g] * 4096);
            const float4 u = Ug[tid];
            const int a0 = (4 * tid) & 31, cc = tid >> 3;
            U_t[a0][cc] = u.x; U_t[a0 + 1][cc] = u.y;
            U_t[a0 + 2][cc] = u.z; U_t[a0 + 3][cc] = u.w;
#pragma unroll
            for (int i = 0; i < 4; ++i) {
                const int i4 = tid + i * 256;
                const float4 v = Vg[i4];
                *(float4*)&V_lds[i4 >> 4][(i4 & 15) * 4] = v;
            }
        }
        // issue next token's x loads (hide under compute)
        if (g + 1 < GTOK) {
            const float4* __restrict__ xg = (const float4*)(x + (size_t)sperm[g + 1] * INF);
            px0 = xg[tid]; px1 = xg[tid + 256];
        }
        __syncthreads();

        // xu[b][cx] = sum_a x[b*32+a] * U[cx][a],  b = bg*8 + jj
        float xacc[8];
#pragma unroll
        for (int jj = 0; jj < 8; ++jj) xacc[jj] = 0.f;
        for (int aa = 0; aa < 32; aa += 4) {
            const float u0 = U_t[aa][cx], u1 = U_t[aa + 1][cx];
            const float u2 = U_t[aa + 2][cx], u3 = U_t[aa + 3][cx];
#pragma unroll
            for (int jj = 0; jj < 8; ++jj) {
                const float4 xv = *(const float4*)&x_lds[(bg * 8 + jj) * 32 + aa];
                xacc[jj] += xv.x * u0 + xv.y * u1 + xv.z * u2 + xv.w * u3;
            }
        }
#pragma unroll
        for (int jj = 0; jj < 8; ++jj) xu_t[cx][bg * 8 + jj] = xacc[jj];
        __syncthreads();

        // vxu[d][c] = sum_b V[d][b] * xu[b][c]
        float vtmp[8];
#pragma unroll
        for (int j = 0; j < 8; ++j) vtmp[j] = 0.f;
        for (int b = 0; b < 64; b += 4) {
            const float4 xc0 = *(const float4*)&xu_t[c0][b];
            const float4 xc1 = *(const float4*)&xu_t[c0 + 16][b];
#pragma unroll
            for (int jd = 0; jd < 4; ++jd) {
                const float4 vv = *(const float4*)&V_lds[dgrp + 16 * jd][b];
                vtmp[jd * 2]     += vv.x * xc0.x + vv.y * xc0.y + vv.z * xc0.z + vv.w * xc0.w;
                vtmp[jd * 2 + 1] += vv.x * xc1.x + vv.y * xc1.y + vv.z * xc1.z + vv.w * xc1.w;
            }
        }
#pragma unroll
        for (int j = 0; j < 8; ++j) acc[g][j] += sgain[g] * vtmp[j];
    }

    // ---- scatter stores (16-lane contiguous 64B segments)
#pragma unroll
    for (int g = 0; g < GTOK; ++g) {
        float* __restrict__ orow = out + (size_t)sperm[g] * OUTF;
#pragma unroll
        for (int jd = 0; jd < 4; ++jd)
#pragma unroll
            for (int jc = 0; jc < 2; ++jc)
                orow[(dgrp + 16 * jd) * 32 + c0 + 16 * jc] = acc[g][jd * 2 + jc];
    }
}

extern "C" void kernel_launch(void* const* d_in, const int* in_sizes, int n_in,
                              void* d_out, int out_size, void* d_ws, size_t ws_size,
                              hipStream_t stream) {
    const float* x   = (const float*)d_in[0];
    const int*   rid = (const int*)d_in[1];
    const float* si  = (const float*)d_in[2];
    const float* so  = (const float*)d_in[3];
    const float* rU  = (const float*)d_in[4];
    const float* rV  = (const float*)d_in[5];
    const float* rg  = (const float*)d_in[6];
    float* out = (float*)d_out;

    int*   perm = (int*)d_ws;                              // 64 KB
    float* t    = (float*)((char*)d_ws + 65536);           // 2.95 MB

    sort_kernel<<<1, 1024, 0, stream>>>(rid, perm);
    t_gemm3<<<NTOK / 64, 256, 0, stream>>>(x, si, t);
    fused3<<<NTOK / GTOK, 256, 0, stream>>>(x, rid, so, rU, rV, rg, t, perm, out);
}